// Round 4
// baseline (115.188 us; speedup 1.0000x reference)
//
#include <hip/hip_runtime.h>
#include <float.h>

// Chamfer distance, fp32, N=M=16384.
// d(q,t) = |q|^2 + (|t|^2 - 2 q.t). Targets transformed in-kernel into SoA
// LDS segments (TX=-2x, TY=-2y, TZ=-2z, TW=|t|^2), SEG=2048 (32 KB -> 4
// blocks/CU). Each wave register-caches NQ=16 wave-uniform queries; lanes
// stream 2 targets/step via ds_read_b64. Inner math per 2 pairs:
// 6 v_fma_f32 + 1 v_min3_f32 = 3.5 slots/pair (pk_fma is half-rate on
// gfx950 -- no win). Block partials via one atomicAdd(out) each.

#define NPTS 16384
constexpr int NQ   = 16;            // queries per wave
constexpr int NW   = 4;             // waves per block
constexpr int QPB  = NW * NQ;       // 64 queries per block
constexpr int SEG  = 2048;          // targets per LDS pass (4 x 8 KB = 32 KB)
constexpr int NBLK = NPTS / QPB;    // 256 blocks per direction

typedef float v2f __attribute__((ext_vector_type(2)));

__global__ __launch_bounds__(256, 4) void cd_main(const float* __restrict__ gt,
                                                  const float* __restrict__ gen,
                                                  float* __restrict__ out) {
    const int dir = blockIdx.y;                    // 0: gt->gen, 1: gen->gt
    const float* __restrict__ Q = dir ? gen : gt;
    const float* __restrict__ T = dir ? gt : gen;

    __shared__ float TX[SEG], TY[SEG], TZ[SEG], TW[SEG];
    __shared__ float bsum[NW];

    const int lane = threadIdx.x & 63;
    const int wave = __builtin_amdgcn_readfirstlane(threadIdx.x >> 6);

    // Wave-uniform query block.
    const int qbase = blockIdx.x * QPB + wave * NQ;
    float qx[NQ], qy[NQ], qz[NQ], m[NQ];
    #pragma unroll
    for (int i = 0; i < NQ; ++i) {
        qx[i] = Q[3 * (qbase + i) + 0];
        qy[i] = Q[3 * (qbase + i) + 1];
        qz[i] = Q[3 * (qbase + i) + 2];
        m[i]  = FLT_MAX;
    }

    for (int s = 0; s < NPTS; s += SEG) {
        // Stage + transform SEG targets into SoA LDS.
        #pragma unroll
        for (int k = 0; k < SEG / 256; ++k) {      // 8 points per thread
            const int p = k * 256 + threadIdx.x;
            const float x = T[3 * (s + p) + 0];
            const float y = T[3 * (s + p) + 1];
            const float z = T[3 * (s + p) + 2];
            TX[p] = -2.0f * x;
            TY[p] = -2.0f * y;
            TZ[p] = -2.0f * z;
            TW[p] = fmaf(x, x, fmaf(y, y, z * z));
        }
        __syncthreads();

        // Sweep: each step a lane handles 2 consecutive targets vs NQ queries.
        #pragma unroll 2
        for (int st = 0; st < SEG; st += 128) {
            const int b = st + 2 * lane;
            const v2f tx = *(const v2f*)&TX[b];    // ds_read_b64, stride-8B:
            const v2f ty = *(const v2f*)&TY[b];    // covers all 32 banks
            const v2f tz = *(const v2f*)&TZ[b];    // evenly -> conflict-free
            const v2f tw = *(const v2f*)&TW[b];
            #pragma unroll
            for (int i = 0; i < NQ; ++i) {
                const float d0 =
                    fmaf(qx[i], tx.x, fmaf(qy[i], ty.x, fmaf(qz[i], tz.x, tw.x)));
                const float d1 =
                    fmaf(qx[i], tx.y, fmaf(qy[i], ty.y, fmaf(qz[i], tz.y, tw.y)));
                asm("v_min3_f32 %0, %1, %2, %0"
                    : "+v"(m[i]) : "v"(d0), "v"(d1));
            }
        }
        __syncthreads();
    }

    // Cross-lane min per query, then per-wave sum of (min + |q|^2).
    float wsum = 0.0f;
    #pragma unroll
    for (int i = 0; i < NQ; ++i) {
        float v = m[i];
        #pragma unroll
        for (int off = 32; off > 0; off >>= 1)
            v = fminf(v, __shfl_down(v, off, 64));
        wsum += v + fmaf(qx[i], qx[i], fmaf(qy[i], qy[i], qz[i] * qz[i]));
    }
    if (lane == 0) bsum[wave] = wsum;
    __syncthreads();
    if (threadIdx.x == 0)
        atomicAdd(out, (bsum[0] + bsum[1] + bsum[2] + bsum[3]) *
                           (1.0f / (float)NPTS));
}

extern "C" void kernel_launch(void* const* d_in, const int* in_sizes, int n_in,
                              void* d_out, int out_size, void* d_ws, size_t ws_size,
                              hipStream_t stream) {
    const float* gt  = (const float*)d_in[0];
    const float* gen = (const float*)d_in[1];
    float* out       = (float*)d_out;

    hipMemsetAsync(out, 0, sizeof(float) * out_size, stream);  // out is poisoned
    dim3 grid(NBLK, 2);                                        // 256 x 2 blocks
    cd_main<<<grid, 256, 0, stream>>>(gt, gen, out);
}

// Round 5
// 108.280 us; speedup vs baseline: 1.0638x; 1.0638x over previous
//
#include <hip/hip_runtime.h>
#include <float.h>

// Chamfer distance, fp32, N=M=16384.
// d(q,t) = |q|^2 + (|t|^2 - 2 q.t). Targets transformed in-kernel into
// pair-interleaved SoA LDS: TA={-2x0,-2x1,-2y0,-2y1}, TB={-2z0,-2z1,w0,w1}
// (w=|t|^2), so each sweep step is 2 ds_read_b128. Inner math per 2 targets
// per query: 3 v_pk_fma_f32 + 1 v_min3_f32 (pk form measured faster than
// scalar 6-fma form in R3 vs R4). QPB=32 queries/block -> 1024 blocks =
// 4 blocks/CU (32 KB LDS), 4 waves/SIMD for latency hiding.

#define NPTS 16384
constexpr int NQ   = 8;             // queries per wave
constexpr int NW   = 4;             // waves per block
constexpr int QPB  = NW * NQ;       // 32 queries per block
constexpr int SEG  = 2048;          // targets per LDS pass (32 KB)
constexpr int NBLK = NPTS / QPB;    // 512 blocks per direction

typedef float v2f __attribute__((ext_vector_type(2)));

__global__ __launch_bounds__(256, 4) void cd_main(const float* __restrict__ gt,
                                                  const float* __restrict__ gen,
                                                  float* __restrict__ out) {
    const int dir = blockIdx.y;                    // 0: gt->gen, 1: gen->gt
    const float* __restrict__ Q = dir ? gen : gt;
    const float* __restrict__ T = dir ? gt : gen;

    __shared__ float4 TA4[SEG / 2];   // {-2x0,-2x1,-2y0,-2y1} per target pair
    __shared__ float4 TB4[SEG / 2];   // {-2z0,-2z1, w0, w1}
    __shared__ float bsum[NW];

    const int lane = threadIdx.x & 63;
    const int wave = __builtin_amdgcn_readfirstlane(threadIdx.x >> 6);

    // Wave-uniform query block, duplicated into packed pairs.
    const int qbase = blockIdx.x * QPB + wave * NQ;
    v2f qx[NQ], qy[NQ], qz[NQ];
    float m[NQ];
    #pragma unroll
    for (int i = 0; i < NQ; ++i) {
        const float x = Q[3 * (qbase + i) + 0];
        const float y = Q[3 * (qbase + i) + 1];
        const float z = Q[3 * (qbase + i) + 2];
        qx[i] = (v2f){x, x};
        qy[i] = (v2f){y, y};
        qz[i] = (v2f){z, z};
        m[i]  = FLT_MAX;
    }

    for (int s = 0; s < NPTS; s += SEG) {
        // Stage + transform SEG targets (1024 pairs) into interleaved SoA.
        #pragma unroll
        for (int k = 0; k < SEG / 2 / 256; ++k) {   // 4 pairs per thread
            const int j = k * 256 + threadIdx.x;    // pair index in segment
            const float2* p = (const float2*)(T + 3 * (s + 2 * j));
            const float2 f0 = p[0];                 // x0 y0
            const float2 f1 = p[1];                 // z0 x1
            const float2 f2 = p[2];                 // y1 z1
            TA4[j] = make_float4(-2.0f * f0.x, -2.0f * f1.y,
                                 -2.0f * f0.y, -2.0f * f2.x);
            TB4[j] = make_float4(-2.0f * f1.x, -2.0f * f2.y,
                                 fmaf(f0.x, f0.x, fmaf(f0.y, f0.y, f1.x * f1.x)),
                                 fmaf(f1.y, f1.y, fmaf(f2.x, f2.x, f2.y * f2.y)));
        }
        __syncthreads();

        // Sweep: each step a lane handles one target pair vs NQ queries.
        #pragma unroll 2
        for (int st = 0; st < SEG / 2; st += 64) {
            const int b = st + lane;
            const float4 tA = TA4[b];              // ds_read_b128
            const float4 tB = TB4[b];              // ds_read_b128
            const v2f tx = {tA.x, tA.y};
            const v2f ty = {tA.z, tA.w};
            const v2f tz = {tB.x, tB.y};
            const v2f tw = {tB.z, tB.w};
            #pragma unroll
            for (int i = 0; i < NQ; ++i) {
                v2f d;
                asm("v_pk_fma_f32 %0, %1, %2, %3"
                    : "=v"(d) : "v"(qz[i]), "v"(tz), "v"(tw));
                asm("v_pk_fma_f32 %0, %1, %2, %0"
                    : "+v"(d) : "v"(qy[i]), "v"(ty));
                asm("v_pk_fma_f32 %0, %1, %2, %0"
                    : "+v"(d) : "v"(qx[i]), "v"(tx));
                m[i] = fminf(fminf(d.x, d.y), m[i]);   // -> v_min3_f32
            }
        }
        __syncthreads();
    }

    // Cross-lane min per query, then per-wave sum of (min + |q|^2).
    float wsum = 0.0f;
    #pragma unroll
    for (int i = 0; i < NQ; ++i) {
        float v = m[i];
        #pragma unroll
        for (int off = 32; off > 0; off >>= 1)
            v = fminf(v, __shfl_down(v, off, 64));
        const float x = qx[i].x, y = qy[i].x, z = qz[i].x;
        wsum += v + fmaf(x, x, fmaf(y, y, z * z));
    }
    if (lane == 0) bsum[wave] = wsum;
    __syncthreads();
    if (threadIdx.x == 0)
        atomicAdd(out, (bsum[0] + bsum[1] + bsum[2] + bsum[3]) *
                           (1.0f / (float)NPTS));
}

extern "C" void kernel_launch(void* const* d_in, const int* in_sizes, int n_in,
                              void* d_out, int out_size, void* d_ws, size_t ws_size,
                              hipStream_t stream) {
    const float* gt  = (const float*)d_in[0];
    const float* gen = (const float*)d_in[1];
    float* out       = (float*)d_out;

    hipMemsetAsync(out, 0, sizeof(float) * out_size, stream);  // out is poisoned
    dim3 grid(NBLK, 2);                            // 512 x 2 = 1024 blocks
    cd_main<<<grid, 256, 0, stream>>>(gt, gen, out);
}

// Round 6
// 106.260 us; speedup vs baseline: 1.0840x; 1.0190x over previous
//
#include <hip/hip_runtime.h>
#include <float.h>

// Chamfer distance, fp32 in/out, N=M=16384, via bf16 MFMA with split
// compensation. d_ij = |q_i|^2 + (|t_j|^2 - 2 q.t). For each pass
// (row-mins of D, then of D^T), one mfma_f32_16x16x32_bf16 per 16x16 tile
// computes s_ij = -2q.t + |t|^2 exactly enough (K-slots: 9 split-dot terms
// + 3-way-split |t|^2; residual ~1e-5). |q|^2 added in fp32 post-min.
// A-operand = targets (LDS-streamed), B-operand = 16 queries/wave (loaded
// once). B's K=16..31 lanes are zero => A's upper quads are don't-care.

#define NPTS 16384
constexpr int SEG   = 2048;          // targets per LDS segment (64 KB)
constexpr int NSEG  = NPTS / SEG;    // 8
constexpr int STEPS = SEG / 16;      // 128 MFMA steps per segment

typedef __attribute__((ext_vector_type(8))) short short8v;   // 8 bf16
typedef __attribute__((ext_vector_type(4))) float float4v;   // C/D frag

__device__ inline unsigned short f2bf(float x) {             // RNE bf16
    unsigned u = __float_as_uint(x);
    return (unsigned short)((u + 0x7FFFu + ((u >> 16) & 1u)) >> 16);
}
__device__ inline float bf2f(unsigned short b) {
    return __uint_as_float(((unsigned)b) << 16);
}

// Atab[s][i][16] bf16: target-role row  [shx shy shz shx shy shz slx sly slz tnh tnm tnl 0 0 0 0]
// Btab[s][i][16] bf16: query-role row   [qhx qhy qhz qlx qly qlz qhx qhy qhz  1   1   1  0 0 0 0]
// (s = -2*t; terms pair as: sh.qh + sh.ql + sl.qh + tn*1 = -2 q.t + |t|^2)
__global__ __launch_bounds__(256) void cd_prep(const float* __restrict__ gt,
                                               const float* __restrict__ gen,
                                               unsigned short* __restrict__ Atab,
                                               unsigned short* __restrict__ Btab) {
    const int t = blockIdx.x * blockDim.x + threadIdx.x;
    if (t >= 2 * NPTS) return;
    const int s = t >> 14, i = t & (NPTS - 1);
    const float* p = (s ? gen : gt) + 3 * i;
    const float x = p[0], y = p[1], z = p[2];

    const float sx = -2.0f * x, sy = -2.0f * y, sz = -2.0f * z;
    const unsigned short shx = f2bf(sx), shy = f2bf(sy), shz = f2bf(sz);
    const unsigned short slx = f2bf(sx - bf2f(shx));
    const unsigned short sly = f2bf(sy - bf2f(shy));
    const unsigned short slz = f2bf(sz - bf2f(shz));
    const float tn = fmaf(x, x, fmaf(y, y, z * z));
    const unsigned short tnh = f2bf(tn);
    const float r1 = tn - bf2f(tnh);
    const unsigned short tnm = f2bf(r1);
    const unsigned short tnl = f2bf(r1 - bf2f(tnm));

    const unsigned short qhx = f2bf(x), qhy = f2bf(y), qhz = f2bf(z);
    const unsigned short qlx = f2bf(x - bf2f(qhx));
    const unsigned short qly = f2bf(y - bf2f(qhy));
    const unsigned short qlz = f2bf(z - bf2f(qhz));
    const unsigned short ONE = 0x3F80;

    const size_t base = ((size_t)s * NPTS + i) * 16;
    unsigned short a[16] = {shx, shy, shz, shx, shy, shz, slx, sly, slz,
                            tnh, tnm, tnl, 0, 0, 0, 0};
    unsigned short b[16] = {qhx, qhy, qhz, qlx, qly, qlz, qhx, qhy, qhz,
                            ONE, ONE, ONE, 0, 0, 0, 0};
    ((short8v*)(Atab + base))[0] = *(const short8v*)&a[0];
    ((short8v*)(Atab + base))[1] = *(const short8v*)&a[8];
    ((short8v*)(Btab + base))[0] = *(const short8v*)&b[0];
    ((short8v*)(Btab + base))[1] = *(const short8v*)&b[8];
}

__global__ __launch_bounds__(256) void cd_main(const float* __restrict__ gt,
                                               const float* __restrict__ gen,
                                               const unsigned short* __restrict__ Atab,
                                               const unsigned short* __restrict__ Btab,
                                               float* __restrict__ out) {
    const int pass = blockIdx.y;                  // 0: gt queries, 1: gen queries
    const float* __restrict__ Q = pass ? gen : gt;
    const unsigned short* Arows = Atab + (size_t)(1 - pass) * NPTS * 16;
    const unsigned short* Brows = Btab + (size_t)pass * NPTS * 16;

    __shared__ float4 segA[SEG * 2];              // SEG targets x 32 B
    __shared__ float wsum[4];

    const int lane = threadIdx.x & 63;
    const int wave = threadIdx.x >> 6;
    const int m    = lane & 15;                   // query col within tile
    const int quad = lane >> 4;

    // B fragment: 16 queries for this wave, loaded once. Quads 2/3 (K=16..31)
    // are zero => upper-K A inputs are don't-care.
    const int qi = (blockIdx.x * 4 + wave) * 16 + m;
    short8v bfrag;
    {
        union { float4 f; short8v s; } u;
        u.f = (quad < 2) ? ((const float4*)Brows)[qi * 2 + quad]
                         : make_float4(0.f, 0.f, 0.f, 0.f);
        bfrag = u.s;
    }

    float run = FLT_MAX;
    // Lane's A-frag LDS slot: target row m's 32-B K-row, half (quad&1).
    const int fbase = m * 2 + (quad & 1);

    for (int sg = 0; sg < NSEG; ++sg) {
        __syncthreads();
        const float4* src = (const float4*)Arows + (size_t)sg * (SEG * 2);
        #pragma unroll
        for (int k = 0; k < (SEG * 2) / 256; ++k)   // 16 float4 per thread
            segA[k * 256 + threadIdx.x] = src[k * 256 + threadIdx.x];
        __syncthreads();

        #pragma unroll 4
        for (int st = 0; st < STEPS; ++st) {        // 16 targets per step
            union { float4 f; short8v s; } a;
            a.f = segA[fbase + st * 32];            // ds_read_b128, imm offset
            float4v acc = __builtin_amdgcn_mfma_f32_16x16x32_bf16(
                a.s, bfrag, (float4v)(0.0f), 0, 0, 0);
            // C layout: col=lane&15 (query), row=quad*4+reg (target).
            asm("v_min3_f32 %0, %1, %2, %0" : "+v"(run) : "v"(acc[0]), "v"(acc[1]));
            asm("v_min3_f32 %0, %1, %2, %0" : "+v"(run) : "v"(acc[2]), "v"(acc[3]));
        }
    }

    // Min across quads (each covered a disjoint target-row subset).
    float v = run;
    v = fminf(v, __shfl_xor(v, 16, 64));
    v = fminf(v, __shfl_xor(v, 32, 64));
    // + |q|^2 in fp32 (exact), then sum the wave's 16 queries.
    const float qx = Q[3 * qi], qy = Q[3 * qi + 1], qz = Q[3 * qi + 2];
    float d = v + fmaf(qx, qx, fmaf(qy, qy, qz * qz));
    #pragma unroll
    for (int off = 1; off < 16; off <<= 1) d += __shfl_xor(d, off, 16);
    if (lane == 0) wsum[wave] = d;
    __syncthreads();
    if (threadIdx.x == 0)
        atomicAdd(out, (wsum[0] + wsum[1] + wsum[2] + wsum[3]) *
                           (1.0f / (float)NPTS));
}

extern "C" void kernel_launch(void* const* d_in, const int* in_sizes, int n_in,
                              void* d_out, int out_size, void* d_ws, size_t ws_size,
                              hipStream_t stream) {
    const float* gt  = (const float*)d_in[0];
    const float* gen = (const float*)d_in[1];
    float* out       = (float*)d_out;
    unsigned short* Atab = (unsigned short*)d_ws;                 // 1 MB
    unsigned short* Btab = Atab + (size_t)2 * NPTS * 16;          // 1 MB

    hipMemsetAsync(out, 0, sizeof(float) * out_size, stream);
    cd_prep<<<(2 * NPTS) / 256, 256, 0, stream>>>(gt, gen, Atab, Btab);
    dim3 grid(NPTS / 64, 2);                       // 256 x 2 = 512 blocks
    cd_main<<<grid, 256, 0, stream>>>(gt, gen, Atab, Btab, out);
}